// Round 8
// baseline (333.518 us; speedup 1.0000x reference)
//
#include <hip/hip_runtime.h>
#include <math.h>

typedef __bf16 bf16x8 __attribute__((ext_vector_type(8)));
typedef float f32x4 __attribute__((ext_vector_type(4)));

// ---------- helpers ----------

__device__ __forceinline__ unsigned short f2bf(float f) {
    unsigned int u = __float_as_uint(f);
    u += 0x7FFFu + ((u >> 16) & 1u);   // round-to-nearest-even
    return (unsigned short)(u >> 16);
}

// fast logcosh via HW v_exp/v_log (TRANS pipe). abs err ~1e-6/elem, budget 0.02.
__device__ __forceinline__ float logcosh_fast(float v) {
    float a = fabsf(v);
    float t = __expf(-2.0f * a);
    return a + (__logf(1.0f + t) - 0.6931471805599453f);
}

// DPP row_shr add; after shr 1,2,4,8 lane 15 of each 16-lane row holds row sum.
template <int CTRL>
__device__ __forceinline__ float dppadd(float x) {
    int y = __builtin_amdgcn_update_dpp(0, __float_as_int(x), CTRL, 0xf, 0xf, true);
    return x + __int_as_float(y);
}

__device__ __forceinline__ void gload_lds16(const void* g, void* l) {
    __builtin_amdgcn_global_load_lds(
        (__attribute__((address_space(1))) void*)(void*)g,
        (__attribute__((address_space(3))) void*)l, 16, 0, 0);
}

template <int N>
__device__ __forceinline__ void vmwait() {
    if constexpr (N == 0)       asm volatile("s_waitcnt vmcnt(0)" ::: "memory");
    else if constexpr (N == 8)  asm volatile("s_waitcnt vmcnt(8)" ::: "memory");
    else if constexpr (N == 12) asm volatile("s_waitcnt vmcnt(12)" ::: "memory");
}

#define SBAR()  __builtin_amdgcn_s_barrier()
#define SCHED() __builtin_amdgcn_sched_barrier(0)

// ---------- kernel 1: invert permutations ----------
__global__ __launch_bounds__(256) void k_invert(const int* __restrict__ perms,
                                                int* __restrict__ inv) {
    int t = blockIdx.x * 256 + threadIdx.x;
    int g = t >> 10, n = t & 1023;
    inv[(g << 10) + perms[t]] = n;
}

// ---------- kernel 2: bT[j][k] = bf16(W[inv[g][k]][f]), j = g*16+f ----------
__global__ __launch_bounds__(256) void k_build_bt(const float* __restrict__ W,
                                                  const int* __restrict__ inv,
                                                  unsigned short* __restrict__ bT) {
    int j = blockIdx.x;
    int g = j >> 4, f = j & 15;
    const int* invg = inv + (g << 10);
    size_t rowbase = (size_t)j << 10;
#pragma unroll
    for (int i = 0; i < 4; ++i) {
        int k = (i << 8) + threadIdx.x;
        int n = invg[k];
        bT[rowbase + k] = f2bf(W[(n << 4) + f]);
    }
}

// ---------- kernel 3: x -> bf16, out[row] = v_bias * sum(x[row]) ----------
__global__ __launch_bounds__(256) void k_convert(const float* __restrict__ x,
                                                 const float* __restrict__ vb,
                                                 unsigned short* __restrict__ xb,
                                                 float* __restrict__ out) {
    int row = blockIdx.x, tid = threadIdx.x;
    size_t base = ((size_t)row << 10) + (tid << 2);
    float4 v = *reinterpret_cast<const float4*>(x + base);
    ushort4 h;
    h.x = f2bf(v.x); h.y = f2bf(v.y); h.z = f2bf(v.z); h.w = f2bf(v.w);
    *reinterpret_cast<ushort4*>(xb + base) = h;
    float s = v.x + v.y + v.z + v.w;
#pragma unroll
    for (int off = 32; off > 0; off >>= 1) s += __shfl_down(s, off);
    __shared__ float ls[4];
    if ((tid & 63) == 0) ls[tid >> 6] = s;
    __syncthreads();
    if (tid == 0) out[row] = vb[0] * (ls[0] + ls[1] + ls[2] + ls[3]);
}

// ---------- kernel 4: 128x128 GEMM, A direct global->VGPR, B in LDS ----------
// 4 waves (2m x 2n), per-wave 64x64, acc[4][4] f32x4. 16 K-tiles BK=64.
// Per tile: stage B(t+1) (4 gload_lds, swizzled) -> issue 8 A(t+1) loads (MFMA
// fragment layout, L2-served) -> 8 bF ds_reads -> vmcnt(12) [A(t) landed] +
// lgkm(0) -> 32 MFMA -> vmcnt(8) [own B(t+1) landed] -> SBAR (collective).
// aF double-buffered by 2-tile unroll (static reg indexing). 1 barrier/tile.
// DS traffic/tile ~48KB << MFMA 1240cyc/SIMD -> MFMA-bound; 2 independent
// blocks/CU hide each other's waits.

template <bool STB, bool ISSA, int VMA, int VME>
__device__ __forceinline__ void tile_gemm(
    const unsigned short* __restrict__ Bp,   // LDS buf holding B(t)
    unsigned short* __restrict__ Bdst,       // LDS buf for B(t+1)
    const unsigned short* __restrict__ bsrc, // global B(t+1) src (pre-offset)
    const unsigned short* __restrict__ xsrc, // global A(t+1) src (pre-offset)
    bf16x8 (&aFu)[4][2], bf16x8 (&aFl)[4][2], f32x4 (&acc)[4][4],
    int aoff, int bRow, int po0, int po1, int tid, int wv) {
    // stage B(t+1): 16KB, 4 gload_lds, pre-swizzled source
    if (STB) {
#pragma unroll
        for (int i = 0; i < 4; ++i) {
            int c0 = i * 256 + wv * 64;            // wave-uniform chunk base
            int cc = i * 256 + tid;                // this thread's 16B chunk
            int r = cc >> 3;                       // B-tile row 0..127
            int cs = (cc & 7) ^ (r & 7);
            gload_lds16(bsrc + (r << 10) + (cs << 3), Bdst + (c0 << 3));
        }
    }
    SCHED();
    // A(t+1) fragment loads: lane (lr,lk) -> row wm*64+m*16+lr, k = kk*32+lk*8
    if (ISSA) {
#pragma unroll
        for (int m = 0; m < 4; ++m) {
#pragma unroll
            for (int kk = 0; kk < 2; ++kk)
                aFl[m][kk] = *reinterpret_cast<const bf16x8*>(
                    xsrc + aoff + m * 16384 + kk * 32);
        }
    }
    SCHED();
    // bF(t) from LDS (swizzled)
    bf16x8 bF[4][2];
#pragma unroll
    for (int n = 0; n < 4; ++n) {
        bF[n][0] = *reinterpret_cast<const bf16x8*>(Bp + bRow + po0 + n * 1024);
        bF[n][1] = *reinterpret_cast<const bf16x8*>(Bp + bRow + po1 + n * 1024);
    }
    SCHED();
    vmwait<VMA>();                                        // aF(t) landed
    asm volatile("s_waitcnt lgkmcnt(0)" ::: "memory");    // bF(t) in regs
    SCHED();
    __builtin_amdgcn_s_setprio(1);
#pragma unroll
    for (int m = 0; m < 4; ++m)
#pragma unroll
        for (int n = 0; n < 4; ++n)
#pragma unroll
            for (int kk = 0; kk < 2; ++kk)
                acc[m][n] = __builtin_amdgcn_mfma_f32_16x16x32_bf16(
                    aFu[m][kk], bF[n][kk], acc[m][n], 0, 0, 0);
    __builtin_amdgcn_s_setprio(0);
    SCHED();
    if (VME >= 0) vmwait<VME>();                          // own B(t+1) landed
    SBAR();                                               // collective
}

__global__ __launch_bounds__(256, 2) void k_gemm(const unsigned short* __restrict__ xb,
                                                 const unsigned short* __restrict__ bT,
                                                 const float* __restrict__ bias,
                                                 float* __restrict__ partial, int B) {
    __shared__ unsigned short Bs[2][128 * 64];

    const int tid = threadIdx.x;
    const int lane = tid & 63;
    const int wv = tid >> 6;           // 0..3
    const int wm = wv >> 1;            // 0..1  (M half)
    const int wn = wv & 1;             // 0..1  (N half)
    const int lr = lane & 15;
    const int lk = lane >> 4;

    // XCD-bijective swizzle; within an XCD walk rows for a fixed col-block
    const int fid = blockIdx.y * gridDim.x + blockIdx.x;   // nwg = 4096
    const int cpx = (gridDim.x * gridDim.y) >> 3;          // 512
    const int swz = (fid & 7) * cpx + (fid >> 3);
    const int rowb = swz & 127;
    const int cbx = swz >> 7;          // col block (0..31)
    const int row0 = rowb << 7;
    const int j0 = cbx << 7;

    const unsigned short* xbase = xb + ((size_t)row0 << 10);
    const unsigned short* bbase = bT + ((size_t)j0 << 10);

    const int aoff = (wm * 64 + lr) * 1024 + lk * 8;   // per-lane A offset (shorts)
    const int bRow = (wn * 64 + lr) * 64;              // per-lane B LDS row base
    const int po0 = (lk ^ (lr & 7)) * 8;
    const int po1 = ((4 + lk) ^ (lr & 7)) * 8;

    f32x4 acc[4][4];
#pragma unroll
    for (int m = 0; m < 4; ++m)
#pragma unroll
        for (int n = 0; n < 4; ++n)
            acc[m][n] = {0.f, 0.f, 0.f, 0.f};

    bf16x8 aF0[4][2], aF1[4][2];

    // ---- prologue: stage B(0)->Bs0, B(1)->Bs1; load A(0)->aF0 ----
#pragma unroll
    for (int i = 0; i < 4; ++i) {
        int c0 = i * 256 + wv * 64;
        int cc = i * 256 + tid;
        int r = cc >> 3;
        int cs = (cc & 7) ^ (r & 7);
        gload_lds16(bbase + (r << 10) + (cs << 3), &Bs[0][0] + (c0 << 3));
    }
#pragma unroll
    for (int i = 0; i < 4; ++i) {
        int c0 = i * 256 + wv * 64;
        int cc = i * 256 + tid;
        int r = cc >> 3;
        int cs = (cc & 7) ^ (r & 7);
        gload_lds16(bbase + 64 + (r << 10) + (cs << 3), &Bs[1][0] + (c0 << 3));
    }
    SCHED();
#pragma unroll
    for (int m = 0; m < 4; ++m)
#pragma unroll
        for (int kk = 0; kk < 2; ++kk)
            aF0[m][kk] = *reinterpret_cast<const bf16x8*>(xbase + aoff + m * 16384 + kk * 32);
    SCHED();
    vmwait<8>();   // B(0), B(1) landed (8 newest = A(0) loads)
    SBAR();

    // ---- t = 0: read Bs0, load A(1)->aF1, no stage ----
    tile_gemm<false, true, 8, -1>(&Bs[0][0], &Bs[1][0], bbase, xbase + 64,
                                  aF0, aF1, acc, aoff, bRow, po0, po1, tid, wv);
    // ---- t = 1..14 ----
    for (int tt = 0; tt < 7; ++tt) {
        const int t0 = tt * 2;
        // t odd: read Bs1/aF1; stage B(t+1)->Bs0; load A(t+1)->aF0
        tile_gemm<true, true, 12, 8>(&Bs[1][0], &Bs[0][0],
                                     bbase + ((t0 + 2) << 6), xbase + ((t0 + 2) << 6),
                                     aF1, aF0, acc, aoff, bRow, po0, po1, tid, wv);
        // t even: read Bs0/aF0; stage B(t+1)->Bs1; load A(t+1)->aF1
        tile_gemm<true, true, 12, 8>(&Bs[0][0], &Bs[1][0],
                                     bbase + ((t0 + 3) << 6), xbase + ((t0 + 3) << 6),
                                     aF0, aF1, acc, aoff, bRow, po0, po1, tid, wv);
    }
    // ---- t = 15: read Bs1/aF1, nothing to stage/load ----
    tile_gemm<false, false, 0, -1>(&Bs[1][0], &Bs[0][0], bbase, xbase,
                                   aF1, aF0, acc, aoff, bRow, po0, po1, tid, wv);

    // ---- epilogue: fast logcosh + DPP row-reduce; combine wn halves in LDS ----
    float* rowsum = (float*)&Bs[0][0];   // [2][128]
    const float bv = bias[lr];           // C col % 16 == lane&15
#pragma unroll
    for (int m = 0; m < 4; ++m) {
#pragma unroll
        for (int r = 0; r < 4; ++r) {
            float s = 0.f;
#pragma unroll
            for (int n = 0; n < 4; ++n) s += logcosh_fast(acc[m][n][r] + bv);
            s = dppadd<0x111>(s);
            s = dppadd<0x112>(s);
            s = dppadd<0x114>(s);
            s = dppadd<0x118>(s);
            if (lr == 15)
                rowsum[wn * 128 + wm * 64 + m * 16 + lk * 4 + r] = s;
        }
    }
    __syncthreads();
    if (tid < 128)
        partial[(size_t)cbx * B + row0 + tid] = rowsum[tid] + rowsum[128 + tid];
}

// ---------- kernel 5: out[b] += sum_cb partial[cb][b] ----------
__global__ __launch_bounds__(256) void k_final(const float* __restrict__ partial,
                                               float* __restrict__ out, int ncb, int B) {
    int b = blockIdx.x * 256 + threadIdx.x;
    float s = out[b];
    for (int c = 0; c < ncb; ++c) s += partial[(size_t)c * B + b];
    out[b] = s;
}

// ---------- launch ----------
extern "C" void kernel_launch(void* const* d_in, const int* in_sizes, int n_in,
                              void* d_out, int out_size, void* d_ws, size_t ws_size,
                              hipStream_t stream) {
    const float* x      = (const float*)d_in[0];  // [B,1024]
    const float* W      = (const float*)d_in[1];  // [1024,16]
    const float* bias   = (const float*)d_in[2];  // [16]
    const float* v_bias = (const float*)d_in[3];  // [1]
    const int*   perms  = (const int*)d_in[4];    // [G,1024]
    float* out = (float*)d_out;

    const int N  = 1024;
    const int B  = in_sizes[0] / N;   // 16384
    const int G  = in_sizes[4] / N;   // 256
    const int GF = G * 16;            // 4096
    const int NCB = GF / 128;         // 32 col blocks

    char* w = (char*)d_ws;
    unsigned short* xb = (unsigned short*)w;                           // B*N*2   = 32 MB
    unsigned short* bT = (unsigned short*)(w + (size_t)B * N * 2);     // GF*N*2  = 8 MB
    int* inv = (int*)(w + (size_t)B * N * 2 + (size_t)GF * N * 2);     // G*N*4   = 1 MB
    float* partial = (float*)(w + (size_t)B * N * 2 + (size_t)GF * N * 2
                              + (size_t)G * N * 4);                    // NCB*B*4 = 2 MB

    k_invert<<<G * N / 256, 256, 0, stream>>>(perms, inv);
    k_build_bt<<<GF, 256, 0, stream>>>(W, inv, bT);
    k_convert<<<B, 256, 0, stream>>>(x, v_bias, xb, out);
    k_gemm<<<dim3(NCB, B / 128), 256, 0, stream>>>(xb, bT, bias, partial, B);
    k_final<<<B / 256, 256, 0, stream>>>(partial, out, NCB, B);
}

// Round 9
// 197.489 us; speedup vs baseline: 1.6888x; 1.6888x over previous
//
#include <hip/hip_runtime.h>
#include <math.h>

typedef __bf16 bf16x8 __attribute__((ext_vector_type(8)));
typedef float f32x4 __attribute__((ext_vector_type(4)));

// ---------- helpers ----------

__device__ __forceinline__ unsigned short f2bf(float f) {
    unsigned int u = __float_as_uint(f);
    u += 0x7FFFu + ((u >> 16) & 1u);   // round-to-nearest-even
    return (unsigned short)(u >> 16);
}

// fast logcosh via HW v_exp/v_log (TRANS pipe). abs err ~1e-6/elem, budget 0.02.
__device__ __forceinline__ float logcosh_fast(float v) {
    float a = fabsf(v);
    float t = __expf(-2.0f * a);
    return a + (__logf(1.0f + t) - 0.6931471805599453f);
}

// DPP row_shr add; after shr 1,2,4,8 lane 15 of each 16-lane row holds row sum.
template <int CTRL>
__device__ __forceinline__ float dppadd(float x) {
    int y = __builtin_amdgcn_update_dpp(0, __float_as_int(x), CTRL, 0xf, 0xf, true);
    return x + __int_as_float(y);
}

__device__ __forceinline__ void gload_lds16(const void* g, void* l) {
    __builtin_amdgcn_global_load_lds(
        (__attribute__((address_space(1))) void*)(void*)g,
        (__attribute__((address_space(3))) void*)l, 16, 0, 0);
}

#define SBAR()  __builtin_amdgcn_s_barrier()
#define SCHED() __builtin_amdgcn_sched_barrier(0)

// ---------- kernel 1: invert permutations ----------
__global__ __launch_bounds__(256) void k_invert(const int* __restrict__ perms,
                                                int* __restrict__ inv) {
    int t = blockIdx.x * 256 + threadIdx.x;
    int g = t >> 10, n = t & 1023;
    inv[(g << 10) + perms[t]] = n;
}

// ---------- kernel 2: bT[j][k] = bf16(W[inv[g][k]][f]), j = g*16+f ----------
__global__ __launch_bounds__(256) void k_build_bt(const float* __restrict__ W,
                                                  const int* __restrict__ inv,
                                                  unsigned short* __restrict__ bT) {
    int j = blockIdx.x;
    int g = j >> 4, f = j & 15;
    const int* invg = inv + (g << 10);
    size_t rowbase = (size_t)j << 10;
#pragma unroll
    for (int i = 0; i < 4; ++i) {
        int k = (i << 8) + threadIdx.x;
        int n = invg[k];
        bT[rowbase + k] = f2bf(W[(n << 4) + f]);
    }
}

// ---------- kernel 3: x -> bf16, out[row] = v_bias * sum(x[row]) ----------
__global__ __launch_bounds__(256) void k_convert(const float* __restrict__ x,
                                                 const float* __restrict__ vb,
                                                 unsigned short* __restrict__ xb,
                                                 float* __restrict__ out) {
    int row = blockIdx.x, tid = threadIdx.x;
    size_t base = ((size_t)row << 10) + (tid << 2);
    float4 v = *reinterpret_cast<const float4*>(x + base);
    ushort4 h;
    h.x = f2bf(v.x); h.y = f2bf(v.y); h.z = f2bf(v.z); h.w = f2bf(v.w);
    *reinterpret_cast<ushort4*>(xb + base) = h;
    float s = v.x + v.y + v.z + v.w;
#pragma unroll
    for (int off = 32; off > 0; off >>= 1) s += __shfl_down(s, off);
    __shared__ float ls[4];
    if ((tid & 63) == 0) ls[tid >> 6] = s;
    __syncthreads();
    if (tid == 0) out[row] = vb[0] * (ls[0] + ls[1] + ls[2] + ls[3]);
}

// ---------- kernel 4: 256x256 GEMM, m201 8-phase schedule + fused logcosh -------
// 16 K-tiles BK=64, dbuf LDS, 4 fine phases per K-tile (8 per 2 tiles):
//   ph1: 12 ds_reads (aF0-3,bF0-1) + 2 B(t+1)-stages; SBAR; lgkm(0); 16 MFMA q00; SBAR
//   ph2:  8 ds_reads (aF4-7)       + 2 B(t+1)-stages; SBAR; lgkm(0); q10; SBAR
//   ph3:  4 ds_reads (bF2-3);                         SBAR; lgkm(0); q11; SBAR
//   ph4:  4 A(t+2)-stages;                            SBAR; q01; vmcnt(4); SBAR
// Overlap is CROSS-WAVE (2 waves/SIMD staggered within each phase; setprio favors
// the MFMA-entering wave). WAR: B(t+1)->buf q staged ph1-2 (q's B-reads drained
// t-1.ph3); A(t+2)->buf p staged ph4 (p's A-reads drained t.ph2 lgkm(0)+SBAR).
// RAW: vmcnt(4) at ph4 leaves exactly A(t+2) in flight -> A/B(t+1) landed.

#define MFMA_QUAD(MH, NH)                                                        \
    _Pragma("unroll") for (int m_ = 0; m_ < 4; ++m_)                             \
    _Pragma("unroll") for (int n_ = 0; n_ < 2; ++n_)                             \
    _Pragma("unroll") for (int kk_ = 0; kk_ < 2; ++kk_)                          \
        acc[(MH) * 4 + m_][(NH) * 2 + n_] =                                      \
            __builtin_amdgcn_mfma_f32_16x16x32_bf16(                             \
                aF[(MH) * 4 + m_][kk_], bF[(NH) * 2 + n_][kk_],                  \
                acc[(MH) * 4 + m_][(NH) * 2 + n_], 0, 0, 0);

// stage instr i (of 4) for one 256x64 tile: 512 chunks, thread voff precomputed
__device__ __forceinline__ void stage_i(unsigned short* dst, const unsigned short* src,
                                        int voff, int i, int wv) {
    gload_lds16(src + voff, dst + (((i << 9) + wv * 64) << 3));
}

template <bool STB, bool STA, int VM>
__device__ __forceinline__ void tile_m201(
    const unsigned short* Ap, const unsigned short* Bp,   // read buffers (tile t)
    unsigned short* Bdst,                                  // buf for B(t+1)
    unsigned short* Adst,                                  // buf for A(t+2) (= Ap)
    const unsigned short* bsrc, const unsigned short* xsrc,
    f32x4 (&acc)[8][4], const int (&vs)[4],
    int aRow, int bRow, int po0, int po1, int wv) {
    bf16x8 aF[8][2], bF[4][2];

    // ---- ph1: q00 frags (12 reads) + B(t+1) half0 stages
#pragma unroll
    for (int m = 0; m < 4; ++m) {
        aF[m][0] = *reinterpret_cast<const bf16x8*>(Ap + aRow + po0 + m * 1024);
        aF[m][1] = *reinterpret_cast<const bf16x8*>(Ap + aRow + po1 + m * 1024);
    }
#pragma unroll
    for (int n = 0; n < 2; ++n) {
        bF[n][0] = *reinterpret_cast<const bf16x8*>(Bp + bRow + po0 + n * 1024);
        bF[n][1] = *reinterpret_cast<const bf16x8*>(Bp + bRow + po1 + n * 1024);
    }
    if (STB) { stage_i(Bdst, bsrc, vs[0], 0, wv); stage_i(Bdst, bsrc, vs[1], 1, wv); }
    SCHED(); SBAR();
    asm volatile("s_waitcnt lgkmcnt(0)" ::: "memory");
    SCHED();
    __builtin_amdgcn_s_setprio(1);
    MFMA_QUAD(0, 0)
    __builtin_amdgcn_s_setprio(0);
    SCHED(); SBAR();

    // ---- ph2: aF4-7 (8 reads) + B(t+1) half1 stages
#pragma unroll
    for (int m = 4; m < 8; ++m) {
        aF[m][0] = *reinterpret_cast<const bf16x8*>(Ap + aRow + po0 + m * 1024);
        aF[m][1] = *reinterpret_cast<const bf16x8*>(Ap + aRow + po1 + m * 1024);
    }
    if (STB) { stage_i(Bdst, bsrc, vs[2], 2, wv); stage_i(Bdst, bsrc, vs[3], 3, wv); }
    SCHED(); SBAR();
    asm volatile("s_waitcnt lgkmcnt(0)" ::: "memory");
    SCHED();
    __builtin_amdgcn_s_setprio(1);
    MFMA_QUAD(1, 0)
    __builtin_amdgcn_s_setprio(0);
    SCHED(); SBAR();   // all A-reads of buf p drained in every wave

    // ---- ph3: bF2-3 (4 reads)
#pragma unroll
    for (int n = 2; n < 4; ++n) {
        bF[n][0] = *reinterpret_cast<const bf16x8*>(Bp + bRow + po0 + n * 1024);
        bF[n][1] = *reinterpret_cast<const bf16x8*>(Bp + bRow + po1 + n * 1024);
    }
    SCHED(); SBAR();
    asm volatile("s_waitcnt lgkmcnt(0)" ::: "memory");
    SCHED();
    __builtin_amdgcn_s_setprio(1);
    MFMA_QUAD(1, 1)
    __builtin_amdgcn_s_setprio(0);
    SCHED(); SBAR();

    // ---- ph4: A(t+2) stages (A-region of buf p safe since ph2-end); q01
    if (STA) {
#pragma unroll
        for (int i = 0; i < 4; ++i) stage_i(Adst, xsrc, vs[i], i, wv);
    }
    SCHED(); SBAR();
    __builtin_amdgcn_s_setprio(1);
    MFMA_QUAD(0, 1)
    __builtin_amdgcn_s_setprio(0);
    SCHED();
    if (VM == 4)      { asm volatile("s_waitcnt vmcnt(4)" ::: "memory"); }
    else if (VM == 0) { asm volatile("s_waitcnt vmcnt(0)" ::: "memory"); }
    SCHED(); SBAR();
}

__global__ __launch_bounds__(512, 2) void k_gemm(const unsigned short* __restrict__ xb,
                                                 const unsigned short* __restrict__ bT,
                                                 const float* __restrict__ bias,
                                                 float* __restrict__ partial, int B) {
    __shared__ unsigned short As[2][256 * 64];
    __shared__ unsigned short Bs[2][256 * 64];

    const int tid = threadIdx.x;
    const int lane = tid & 63;
    const int wv = tid >> 6;           // 0..7
    const int wm = wv >> 2;            // 0..1  (M half)
    const int wn = wv & 3;             // 0..3  (N quarter)
    const int lr = lane & 15;
    const int lk = lane >> 4;

    // XCD-bijective swizzle (nwg = 1024, % 8 == 0)
    const int fid = blockIdx.y * gridDim.x + blockIdx.x;
    const int cpx = (gridDim.x * gridDim.y) >> 3;
    const int swz = (fid & 7) * cpx + (fid >> 3);
    const int cbx = swz & 15;          // col block (0..15)
    const int row0 = (swz >> 4) << 8;  // row block * 256
    const int j0 = cbx << 8;

    const unsigned short* xbase = xb + ((size_t)row0 << 10);
    const unsigned short* bbase = bT + ((size_t)j0 << 10);

    // hoisted per-wave LDS read bases (short units); +m*1024 imm offsets
    const int aRow = (wm * 128 + lr) * 64;
    const int bRow = (wn * 64 + lr) * 64;
    const int po0 = (lk ^ (lr & 7)) * 8;
    const int po1 = ((4 + lk) ^ (lr & 7)) * 8;

    // per-thread stage source voffsets (shorts), instr i covers chunks i*512+tid
    int vs[4];
#pragma unroll
    for (int i = 0; i < 4; ++i) {
        int cc = (i << 9) + tid;
        int r = cc >> 3;
        int cs = (cc & 7) ^ (r & 7);
        vs[i] = (r << 10) + (cs << 3);
    }

    f32x4 acc[8][4];
#pragma unroll
    for (int m = 0; m < 8; ++m)
#pragma unroll
        for (int n = 0; n < 4; ++n)
            acc[m][n] = {0.f, 0.f, 0.f, 0.f};

    // ---- prologue: stage A(0),B(0),A(1),B(1); drain tile0 ----
#pragma unroll
    for (int i = 0; i < 4; ++i) stage_i(&As[0][0], xbase, vs[i], i, wv);
#pragma unroll
    for (int i = 0; i < 4; ++i) stage_i(&Bs[0][0], bbase, vs[i], i, wv);
#pragma unroll
    for (int i = 0; i < 4; ++i) stage_i(&As[1][0], xbase + 64, vs[i], i, wv);
#pragma unroll
    for (int i = 0; i < 4; ++i) stage_i(&Bs[1][0], bbase + 64, vs[i], i, wv);
    asm volatile("s_waitcnt vmcnt(8)" ::: "memory");   // A(0),B(0) landed
    SCHED();
    SBAR();

    // ---- t=0: B(1) prestaged; stage A(2) at ph4 ----
    tile_m201<false, true, 4>(&As[0][0], &Bs[0][0], &Bs[1][0], &As[0][0],
                              bbase, xbase + 128,
                              acc, vs, aRow, bRow, po0, po1, wv);
    // ---- t=1..12 (pairs) ----
    for (int tt = 0; tt < 6; ++tt) {
        const int t = 2 * tt + 1;          // odd: bufs As1/Bs1
        tile_m201<true, true, 4>(&As[1][0], &Bs[1][0], &Bs[0][0], &As[1][0],
                                 bbase + ((t + 1) << 6), xbase + ((t + 2) << 6),
                                 acc, vs, aRow, bRow, po0, po1, wv);
        tile_m201<true, true, 4>(&As[0][0], &Bs[0][0], &Bs[1][0], &As[0][0],
                                 bbase + ((t + 2) << 6), xbase + ((t + 3) << 6),
                                 acc, vs, aRow, bRow, po0, po1, wv);
    }
    // ---- t=13: stage B(14), A(15) ----
    tile_m201<true, true, 4>(&As[1][0], &Bs[1][0], &Bs[0][0], &As[1][0],
                             bbase + (14 << 6), xbase + (15 << 6),
                             acc, vs, aRow, bRow, po0, po1, wv);
    // ---- t=14: stage B(15) only; drain all ----
    tile_m201<true, false, 0>(&As[0][0], &Bs[0][0], &Bs[1][0], &As[0][0],
                              bbase + (15 << 6), xbase,
                              acc, vs, aRow, bRow, po0, po1, wv);
    // ---- t=15: no stages ----
    tile_m201<false, false, -1>(&As[1][0], &Bs[1][0], &Bs[0][0], &As[1][0],
                                bbase, xbase,
                                acc, vs, aRow, bRow, po0, po1, wv);

    // ---- epilogue: fast logcosh + DPP row-reduce; reuse As as scratch ----
    float* rowsum = (float*)&As[0][0];   // [4][256]
    const float bv = bias[lr];           // C col % 16 == lane&15
#pragma unroll
    for (int m = 0; m < 8; ++m) {
#pragma unroll
        for (int r = 0; r < 4; ++r) {
            float s = 0.f;
#pragma unroll
            for (int n = 0; n < 4; ++n) s += logcosh_fast(acc[m][n][r] + bv);
            s = dppadd<0x111>(s);
            s = dppadd<0x112>(s);
            s = dppadd<0x114>(s);
            s = dppadd<0x118>(s);
            if (lr == 15)
                rowsum[wn * 256 + wm * 128 + m * 16 + lk * 4 + r] = s;
        }
    }
    __syncthreads();
    if (tid < 256) {
        float s = rowsum[tid] + rowsum[256 + tid] + rowsum[512 + tid] + rowsum[768 + tid];
        partial[(size_t)cbx * B + row0 + tid] = s;
    }
}

// ---------- kernel 5: out[b] += sum_cb partial[cb][b] ----------
__global__ __launch_bounds__(256) void k_final(const float* __restrict__ partial,
                                               float* __restrict__ out, int ncb, int B) {
    int b = blockIdx.x * 256 + threadIdx.x;
    float s = out[b];
    for (int c = 0; c < ncb; ++c) s += partial[(size_t)c * B + b];
    out[b] = s;
}

// ---------- launch ----------
extern "C" void kernel_launch(void* const* d_in, const int* in_sizes, int n_in,
                              void* d_out, int out_size, void* d_ws, size_t ws_size,
                              hipStream_t stream) {
    const float* x      = (const float*)d_in[0];  // [B,1024]
    const float* W      = (const float*)d_in[1];  // [1024,16]
    const float* bias   = (const float*)d_in[2];  // [16]
    const float* v_bias = (const float*)d_in[3];  // [1]
    const int*   perms  = (const int*)d_in[4];    // [G,1024]
    float* out = (float*)d_out;

    const int N  = 1024;
    const int B  = in_sizes[0] / N;   // 16384
    const int G  = in_sizes[4] / N;   // 256
    const int GF = G * 16;            // 4096
    const int NCB = GF / 256;         // 16 col blocks

    char* w = (char*)d_ws;
    unsigned short* xb = (unsigned short*)w;                           // B*N*2   = 32 MB
    unsigned short* bT = (unsigned short*)(w + (size_t)B * N * 2);     // GF*N*2  = 8 MB
    int* inv = (int*)(w + (size_t)B * N * 2 + (size_t)GF * N * 2);     // G*N*4   = 1 MB
    float* partial = (float*)(w + (size_t)B * N * 2 + (size_t)GF * N * 2
                              + (size_t)G * N * 4);                    // NCB*B*4 = 1 MB

    k_invert<<<G * N / 256, 256, 0, stream>>>(perms, inv);
    k_build_bt<<<GF, 256, 0, stream>>>(W, inv, bT);
    k_convert<<<B, 256, 0, stream>>>(x, v_bias, xb, out);
    k_gemm<<<dim3(NCB, B / 256), 512, 0, stream>>>(xb, bT, bias, partial, B);
    k_final<<<B / 256, 256, 0, stream>>>(partial, out, NCB, B);
}